// Round 9
// baseline (287.654 us; speedup 1.0000x reference)
//
#include <hip/hip_runtime.h>
#include <math.h>

#define CAT    134
#define NRBF   6
#define ADIM   42
#define NBIL   8
#define KPAD   144      // 9 k-steps of 16 (k=134 is the bias column)
#define CHPAD  160      // 5 waves x 32 channels
#define MSTR   152      // m LDS row stride (shorts): 304 B, 16B-aligned
#define TSTR   168      // mae row stride (shorts): 336 B, 16B-aligned
#define TE     32       // edges per tile
#define M2     (TE * 67)   // float2 count of one m tile (32*134/2)

typedef __bf16 bf16x8 __attribute__((ext_vector_type(8)));
typedef float  f32x16 __attribute__((ext_vector_type(16)));
typedef float  f32x4  __attribute__((ext_vector_type(4)));

__device__ __forceinline__ unsigned short f32_bf16_rne(float x) {
    union { float f; unsigned u; } v; v.f = x;
    unsigned u = v.u;
    u += 0x7FFFu + ((u >> 16) & 1u);
    return (unsigned short)(u >> 16);
}
__device__ __forceinline__ float bf16_f32(unsigned short h) {
    union { float f; unsigned u; } v; v.u = ((unsigned)h) << 16;
    return v.f;
}
// trunc split: a = hi + lo, |err| ~ 2^-17 |a|
__device__ __forceinline__ void split_pack(float a, float b, unsigned& ph, unsigned& pl) {
    unsigned ua = __float_as_uint(a), ub = __float_as_uint(b);
    ph = (ua >> 16) | (ub & 0xffff0000u);
    float ra = a - __uint_as_float(ua & 0xffff0000u);
    float rb = b - __uint_as_float(ub & 0xffff0000u);
    pl = (__float_as_uint(ra) >> 16) | (__float_as_uint(rb) & 0xffff0000u);
}

// ---------------------------------------------------------------------------
// prep: pack weights into FRAGMENT-MAJOR layout so in-kernel fragment loads
// are fully coalesced:  WF[((wv*9+ks)*64+lane)*16 + {j | 8+j}] = {hi | lo}
// ---------------------------------------------------------------------------
__global__ __launch_bounds__(256) void prep_kernel(
    const float* __restrict__ Wm, const float* __restrict__ bm,
    const float* __restrict__ We, const float* __restrict__ fw,
    unsigned short* __restrict__ WF, unsigned short* __restrict__ WeF,
    unsigned short* __restrict__ FwF)
{
    int i = blockIdx.x * 256 + threadIdx.x;
    if (i < CHPAD * KPAD) {                                  // W_m (+bias col)
        int c = i / KPAD, k = i - c * KPAD;
        float v = 0.f;
        if (c < CAT) {
            if (k < CAT) v = Wm[c * CAT + k];
            else if (k == CAT) v = bm[c];
        }
        unsigned short h = f32_bf16_rne(v);
        unsigned short l = f32_bf16_rne(v - bf16_f32(h));
        int wv = c >> 5, l31 = c & 31, ks = k >> 4;
        int lane = ((k >> 3) & 1) * 32 + l31, j = k & 7;
        size_t idx = ((size_t)(wv * 9 + ks) * 64 + lane) * 16 + j;
        WF[idx] = h; WF[idx + 8] = l;
    } else if (i < CHPAD * KPAD + CHPAD * 16) {              // W_e (K -> 16)
        int j2 = i - CHPAD * KPAD; int c = j2 >> 4, r = j2 & 15;
        float v = (c < CAT && r < NRBF) ? We[c * NRBF + r] : 0.f;
        unsigned short h = f32_bf16_rne(v);
        unsigned short l = f32_bf16_rne(v - bf16_f32(h));
        int wv = c >> 5, l31 = c & 31;
        int lane = (r >> 3) * 32 + l31, j = r & 7;
        size_t idx = ((size_t)wv * 64 + lane) * 16 + j;
        WeF[idx] = h; WeF[idx + 8] = l;
    } else if (i < CHPAD * KPAD + CHPAD * 16 + 16 * CHPAD) { // final_w (16 rows)
        int j3 = i - CHPAD * KPAD - CHPAD * 16;
        int r = j3 / CHPAD, c = j3 - r * CHPAD;
        float v = (r < NRBF && c < CAT) ? fw[r * CAT + c] : 0.f;
        unsigned short h = f32_bf16_rne(v);
        unsigned short l = f32_bf16_rne(v - bf16_f32(h));
        int wv = c >> 5, kk = c & 31;
        int lane = (kk >> 3) * 16 + r, j = kk & 7;
        size_t idx = ((size_t)wv * 64 + lane) * 16 + j;
        FwF[idx] = h; FwF[idx + 8] = l;
    }
}

// ---------------------------------------------------------------------------
// angle: s_a = dot(a_sbf[a,:], colsum(W_a)), scatter-add into sum_s[kj]
// ---------------------------------------------------------------------------
__global__ __launch_bounds__(256) void angle_kernel(
    const float* __restrict__ a_sbf, const int* __restrict__ kj_idx,
    const float* __restrict__ W_a, float* __restrict__ sum_s, int A)
{
    __shared__ float wsum[ADIM];
    int tid = threadIdx.x;
    if (tid < ADIM) {
        float s = 0.f;
        #pragma unroll
        for (int b = 0; b < NBIL; ++b) s += W_a[b * ADIM + tid];
        wsum[tid] = s;
    }
    __syncthreads();

    int a = blockIdx.x * 256 + tid;
    if (a >= A) return;

    const float* row = a_sbf + (size_t)a * ADIM;
    float s = 0.f;
    #pragma unroll
    for (int d2 = 0; d2 < ADIM / 2; ++d2) {
        float2 v = *reinterpret_cast<const float2*>(row + d2 * 2);
        s += v.x * wsum[d2 * 2] + v.y * wsum[d2 * 2 + 1];
    }
    atomicAdd(&sum_s[kj_idx[a]], s);
}

// Zero-instruction opaque pin (kept from round 7 — it helped scheduling).
#define PIN_WEIGHTS()                                                          \
    asm volatile("" :                                                         \
        "+v"(wfh[0]), "+v"(wfh[1]), "+v"(wfh[2]), "+v"(wfh[3]), "+v"(wfh[4]), \
        "+v"(wfh[5]), "+v"(wfh[6]), "+v"(wfh[7]), "+v"(wfh[8]),               \
        "+v"(wfl[0]), "+v"(wfl[1]), "+v"(wfl[2]), "+v"(wfl[3]), "+v"(wfl[4]), \
        "+v"(wfl[5]), "+v"(wfl[6]), "+v"(wfl[7]), "+v"(wfl[8]),               \
        "+v"(weh), "+v"(wel), "+v"(fwh), "+v"(fwl))

// ---------------------------------------------------------------------------
// edge: 32-edge tiles, 5 waves. Identical to round-7 kernel EXCEPT MFMA1 is
// split into 3 independent accumulator chains by product type (Wh*mh, Wl*mh,
// Wh*ml) so dependency distance = issue distance -> MFMA latency hidden even
// at 1-2 waves/SIMD. MFMA3 split into 2 chains per subtile. 2 barriers/tile.
// ---------------------------------------------------------------------------
__global__ __launch_bounds__(320, 3) void edge_kernel(
    const float* __restrict__ m_ji, const float* __restrict__ e_rbf,
    const unsigned short* __restrict__ WF, const unsigned short* __restrict__ WeF,
    const unsigned short* __restrict__ FwF,
    const float* __restrict__ sum_s, float* __restrict__ out, int E, int NT)
{
    __shared__ unsigned short mhs[TE][MSTR];    //  9728 B
    __shared__ unsigned short mls[TE][MSTR];    //  9728 B
    __shared__ unsigned short ebh[TE][16];      //  1024 B
    __shared__ unsigned short ebl[TE][16];      //  1024 B
    __shared__ unsigned short maeh[TE][TSTR];   // 10752 B
    __shared__ unsigned short mael[TE][TSTR];   // 10752 B
    __shared__ float projp[5][TE][8];           //  5120 B  -> 48128 B total

    const int tid = threadIdx.x;
    const int l   = tid & 63;
    const int wv  = __builtin_amdgcn_readfirstlane(tid >> 6);
    const int l31 = l & 31;
    const int hi5 = l >> 5;

    // ---- persistent weight fragments (normal loads, then opaque pin) -----
    bf16x8 wfh[9], wfl[9];
    #pragma unroll
    for (int ks = 0; ks < 9; ++ks) {
        const unsigned short* p = WF + ((size_t)(wv * 9 + ks) * 64 + l) * 16;
        wfh[ks] = *reinterpret_cast<const bf16x8*>(p);
        wfl[ks] = *reinterpret_cast<const bf16x8*>(p + 8);
    }
    const unsigned short* pe = WeF + ((size_t)wv * 64 + l) * 16;
    bf16x8 weh = *reinterpret_cast<const bf16x8*>(pe);
    bf16x8 wel = *reinterpret_cast<const bf16x8*>(pe + 8);
    const unsigned short* pf = FwF + ((size_t)wv * 64 + l) * 16;
    bf16x8 fwh = *reinterpret_cast<const bf16x8*>(pf);
    bf16x8 fwl = *reinterpret_cast<const bf16x8*>(pf + 8);
    PIN_WEIGHTS();

    // ---- one-time LDS init: m bias/pad cols (134..143), eb pad (6..15) ---
    if (tid < 160) {
        int r = tid / 5, j = tid - r * 5;
        *reinterpret_cast<unsigned*>(&mhs[r][134 + 2 * j]) = (j == 0) ? 0x00003F80u : 0u;
        *reinterpret_cast<unsigned*>(&mls[r][134 + 2 * j]) = 0u;
        *reinterpret_cast<unsigned*>(&ebh[r][6 + 2 * j]) = 0u;
        *reinterpret_cast<unsigned*>(&ebl[r][6 + 2 * j]) = 0u;
    }

    // ---- prologue prefetch ------------------------------------------------
    float2 mpre[7]; float2 epre = make_float2(0.f, 0.f);
    {
        int t0 = blockIdx.x;
        if (t0 < NT) {
            const float2* mb = reinterpret_cast<const float2*>(m_ji + (size_t)t0 * TE * CAT);
            int nv2 = min(TE, E - t0 * TE) * 67;
            #pragma unroll
            for (int i = 0; i < 7; ++i) {
                int f = tid + i * 320;
                mpre[i] = (f < nv2) ? mb[f] : make_float2(0.f, 0.f);
            }
            const float2* ebp = reinterpret_cast<const float2*>(e_rbf + (size_t)t0 * TE * NRBF);
            int nve = min(TE, E - t0 * TE) * 3;
            if (tid < 96) epre = (tid < nve) ? ebp[tid] : make_float2(0.f, 0.f);
        }
    }

    for (int t = blockIdx.x; t < NT; t += gridDim.x) {
        const int e0 = t * TE;
        PIN_WEIGHTS();   // re-assert register residency each iteration (0 instrs)

        // ---- convert prefetched tile -> split-bf16 LDS (ONCE per value) --
        #pragma unroll
        for (int i = 0; i < 7; ++i) {
            int f = tid + i * 320;
            if (f < M2) {
                int r = f / 67, c = f - r * 67;
                unsigned h, lo2; split_pack(mpre[i].x, mpre[i].y, h, lo2);
                *reinterpret_cast<unsigned*>(&mhs[r][2 * c]) = h;
                *reinterpret_cast<unsigned*>(&mls[r][2 * c]) = lo2;
            }
        }
        if (tid < 96) {
            int r = tid / 3, j = tid - r * 3;
            unsigned h, lo2; split_pack(epre.x, epre.y, h, lo2);
            *reinterpret_cast<unsigned*>(&ebh[r][2 * j]) = h;
            *reinterpret_cast<unsigned*>(&ebl[r][2 * j]) = lo2;
        }
        __syncthreads();   // barrier A: tile staged

        // ---- issue next tile's global loads (ride under MFMA phases) -----
        {
            int tn = t + gridDim.x;
            if (tn < NT) {
                const float2* mb = reinterpret_cast<const float2*>(m_ji + (size_t)tn * TE * CAT);
                int nv2 = min(TE, E - tn * TE) * 67;
                #pragma unroll
                for (int i = 0; i < 7; ++i) {
                    int f = tid + i * 320;
                    mpre[i] = (f < nv2) ? mb[f] : make_float2(0.f, 0.f);
                }
                const float2* ebp = reinterpret_cast<const float2*>(e_rbf + (size_t)tn * TE * NRBF);
                int nve = min(TE, E - tn * TE) * 3;
                if (tid < 96) epre = (tid < nve) ? ebp[tid] : make_float2(0.f, 0.f);
            }
        }

        // ---- MFMA1: x = Wm.m (+bias); 3 independent chains by product ----
        f32x16 accA = {0,0,0,0,0,0,0,0,0,0,0,0,0,0,0,0};   // Wh*mh
        f32x16 accB = {0,0,0,0,0,0,0,0,0,0,0,0,0,0,0,0};   // Wl*mh
        f32x16 accC = {0,0,0,0,0,0,0,0,0,0,0,0,0,0,0,0};   // Wh*ml
        f32x16 acct = {0,0,0,0,0,0,0,0,0,0,0,0,0,0,0,0};
        #pragma unroll
        for (int ks = 0; ks < 9; ++ks) {
            bf16x8 bh = *reinterpret_cast<const bf16x8*>(&mhs[l31][ks * 16 + hi5 * 8]);
            bf16x8 bl = *reinterpret_cast<const bf16x8*>(&mls[l31][ks * 16 + hi5 * 8]);
            accA = __builtin_amdgcn_mfma_f32_32x32x16_bf16(wfh[ks], bh, accA, 0, 0, 0);
            accB = __builtin_amdgcn_mfma_f32_32x32x16_bf16(wfl[ks], bh, accB, 0, 0, 0);
            accC = __builtin_amdgcn_mfma_f32_32x32x16_bf16(wfh[ks], bl, accC, 0, 0, 0);
        }
        // ---- te = We . eb (short chain, interleaves with MFMA1 tail) -----
        {
            bf16x8 bh = *reinterpret_cast<const bf16x8*>(&ebh[l31][hi5 * 8]);
            bf16x8 bl = *reinterpret_cast<const bf16x8*>(&ebl[l31][hi5 * 8]);
            acct = __builtin_amdgcn_mfma_f32_32x32x16_bf16(weh, bh, acct, 0, 0, 0);
            acct = __builtin_amdgcn_mfma_f32_32x32x16_bf16(wel, bh, acct, 0, 0, 0);
            acct = __builtin_amdgcn_mfma_f32_32x32x16_bf16(weh, bl, acct, 0, 0, 0);
        }

        // ---- mae = silu(x)*te -> split -> wave-private LDS slice ---------
        #pragma unroll
        for (int q = 0; q < 4; ++q) {
            float mz[4];
            #pragma unroll
            for (int i = 0; i < 4; ++i) {
                float x  = accA[q * 4 + i] + accB[q * 4 + i] + accC[q * 4 + i];
                float sg = x / (1.f + __expf(-x));
                mz[i] = sg * acct[q * 4 + i];
            }
            unsigned h0, h1, q0, q1;
            split_pack(mz[0], mz[1], h0, q0);
            split_pack(mz[2], mz[3], h1, q1);
            const int cq = 32 * wv + 8 * q + 4 * hi5;
            *reinterpret_cast<uint2*>(&maeh[l31][cq]) = make_uint2(h0, h1);
            *reinterpret_cast<uint2*>(&mael[l31][cq]) = make_uint2(q0, q1);
        }

        // ---- MFMA3: wave reads ONLY its own mae slice; 2 chains per nt ---
        #pragma unroll
        for (int nt = 0; nt < 2; ++nt) {
            f32x4 a3a = {0, 0, 0, 0};
            f32x4 a3b = {0, 0, 0, 0};
            const int mr = nt * 16 + (l & 15);
            bf16x8 bh = *reinterpret_cast<const bf16x8*>(&maeh[mr][32 * wv + (l >> 4) * 8]);
            bf16x8 bl = *reinterpret_cast<const bf16x8*>(&mael[mr][32 * wv + (l >> 4) * 8]);
            a3a = __builtin_amdgcn_mfma_f32_16x16x32_bf16(fwh, bh, a3a, 0, 0, 0);
            a3b = __builtin_amdgcn_mfma_f32_16x16x32_bf16(fwl, bh, a3b, 0, 0, 0);
            a3a = __builtin_amdgcn_mfma_f32_16x16x32_bf16(fwh, bl, a3a, 0, 0, 0);
            const int g4 = l >> 4, es = nt * 16 + (l & 15);
            if (g4 == 0) {
                f32x4 s4;
                s4[0] = a3a[0] + a3b[0]; s4[1] = a3a[1] + a3b[1];
                s4[2] = a3a[2] + a3b[2]; s4[3] = a3a[3] + a3b[3];
                *reinterpret_cast<f32x4*>(&projp[wv][es][0]) = s4;   // rows 0-3
            } else if (g4 == 1) {
                projp[wv][es][4] = a3a[0] + a3b[0];                  // rows 4-5
                projp[wv][es][5] = a3a[1] + a3b[1];
            }
        }
        __syncthreads();   // barrier B: projp complete, LDS m free to reuse

        // ---- cross-wave reduce + scale + store ---------------------------
        if (tid < 192) {
            const int es = tid / 6, r = tid - es * 6;
            const int eo = e0 + es;
            if (eo < E) {
                float vsum = projp[0][es][r] + projp[1][es][r] + projp[2][es][r]
                           + projp[3][es][r] + projp[4][es][r];
                out[(size_t)eo * NRBF + r] = vsum * sum_s[eo];
            }
        }
    }
}

// ---------------------------------------------------------------------------
extern "C" void kernel_launch(void* const* d_in, const int* in_sizes, int n_in,
                              void* d_out, int out_size, void* d_ws, size_t ws_size,
                              hipStream_t stream)
{
    const float* m_ji    = (const float*)d_in[0];
    // d_in[1] nbr_list, d_in[2] angle_list: unused by the reference math
    const float* e_rbf   = (const float*)d_in[3];
    const float* a_sbf   = (const float*)d_in[4];
    const int*   kj_idx  = (const int*)  d_in[5];
    const float* W_m     = (const float*)d_in[6];
    const float* b_m     = (const float*)d_in[7];
    const float* W_e     = (const float*)d_in[8];
    const float* W_a     = (const float*)d_in[9];
    const float* final_w = (const float*)d_in[10];
    float* out = (float*)d_out;

    const int E  = in_sizes[0] / CAT;
    const int A  = in_sizes[5];
    const int NT = (E + TE - 1) / TE;

    // workspace layout
    char* ws = (char*)d_ws;
    float* sum_s = (float*)ws;
    size_t off = ((size_t)E * 4 + 255) & ~(size_t)255;
    unsigned short* WF  = (unsigned short*)(ws + off); off += (size_t)5 * 9 * 64 * 16 * 2;
    unsigned short* WeF = (unsigned short*)(ws + off); off += (size_t)5 * 64 * 16 * 2;
    unsigned short* FwF = (unsigned short*)(ws + off); off += (size_t)5 * 64 * 16 * 2;

    hipMemsetAsync(sum_s, 0, (size_t)E * sizeof(float), stream);

    const int prep_n = CHPAD * KPAD + CHPAD * 16 + 16 * CHPAD;
    prep_kernel<<<(prep_n + 255) / 256, 256, 0, stream>>>(
        W_m, b_m, W_e, final_w, WF, WeF, FwF);
    angle_kernel<<<(A + 255) / 256, 256, 0, stream>>>(a_sbf, kj_idx, W_a, sum_s, A);

    int grid = 512; if (grid > NT) grid = NT;
    edge_kernel<<<grid, 320, 0, stream>>>(m_ji, e_rbf, WF, WeF, FwF,
                                          sum_s, out, E, NT);
}

// Round 10
// 223.874 us; speedup vs baseline: 1.2849x; 1.2849x over previous
//
#include <hip/hip_runtime.h>
#include <math.h>

#define CAT    134
#define NRBF   6
#define ADIM   42
#define NBIL   8
#define KPAD   144      // 9 k-steps of 16 (k=134 is the bias column)
#define CHPAD  160      // 5 waves x 32 channels
#define MSTR   152      // m LDS row stride (shorts): 304 B, 16B-aligned
#define TSTR   168      // mae row stride (shorts): 336 B, 16B-aligned
#define TE     32       // edges per tile
#define M2     (TE * 67)   // float2 count of one m tile (32*134/2)

typedef __bf16 bf16x8 __attribute__((ext_vector_type(8)));
typedef float  f32x16 __attribute__((ext_vector_type(16)));
typedef float  f32x4  __attribute__((ext_vector_type(4)));

__device__ __forceinline__ unsigned short f32_bf16_rne(float x) {
    union { float f; unsigned u; } v; v.f = x;
    unsigned u = v.u;
    u += 0x7FFFu + ((u >> 16) & 1u);
    return (unsigned short)(u >> 16);
}
__device__ __forceinline__ float bf16_f32(unsigned short h) {
    union { float f; unsigned u; } v; v.u = ((unsigned)h) << 16;
    return v.f;
}
// trunc split: a = hi + lo, |err| ~ 2^-17 |a|
__device__ __forceinline__ void split_pack(float a, float b, unsigned& ph, unsigned& pl) {
    unsigned ua = __float_as_uint(a), ub = __float_as_uint(b);
    ph = (ua >> 16) | (ub & 0xffff0000u);
    float ra = a - __uint_as_float(ua & 0xffff0000u);
    float rb = b - __uint_as_float(ub & 0xffff0000u);
    pl = (__float_as_uint(ra) >> 16) | (__float_as_uint(rb) & 0xffff0000u);
}
__device__ __forceinline__ bf16x8 upack(unsigned a, unsigned b, unsigned c, unsigned d) {
    union { unsigned u[4]; bf16x8 v; } t;
    t.u[0] = a; t.u[1] = b; t.u[2] = c; t.u[3] = d;
    return t.v;
}

// ---------------------------------------------------------------------------
// prep: pack weights into FRAGMENT-MAJOR layout so in-kernel fragment loads
// are fully coalesced:  WF[((wv*9+ks)*64+lane)*16 + {j | 8+j}] = {hi | lo}
// ---------------------------------------------------------------------------
__global__ __launch_bounds__(256) void prep_kernel(
    const float* __restrict__ Wm, const float* __restrict__ bm,
    const float* __restrict__ We, const float* __restrict__ fw,
    unsigned short* __restrict__ WF, unsigned short* __restrict__ WeF,
    unsigned short* __restrict__ FwF)
{
    int i = blockIdx.x * 256 + threadIdx.x;
    if (i < CHPAD * KPAD) {                                  // W_m (+bias col)
        int c = i / KPAD, k = i - c * KPAD;
        float v = 0.f;
        if (c < CAT) {
            if (k < CAT) v = Wm[c * CAT + k];
            else if (k == CAT) v = bm[c];
        }
        unsigned short h = f32_bf16_rne(v);
        unsigned short l = f32_bf16_rne(v - bf16_f32(h));
        int wv = c >> 5, l31 = c & 31, ks = k >> 4;
        int lane = ((k >> 3) & 1) * 32 + l31, j = k & 7;
        size_t idx = ((size_t)(wv * 9 + ks) * 64 + lane) * 16 + j;
        WF[idx] = h; WF[idx + 8] = l;
    } else if (i < CHPAD * KPAD + CHPAD * 16) {              // W_e (K -> 16)
        int j2 = i - CHPAD * KPAD; int c = j2 >> 4, r = j2 & 15;
        float v = (c < CAT && r < NRBF) ? We[c * NRBF + r] : 0.f;
        unsigned short h = f32_bf16_rne(v);
        unsigned short l = f32_bf16_rne(v - bf16_f32(h));
        int wv = c >> 5, l31 = c & 31;
        int lane = (r >> 3) * 32 + l31, j = r & 7;
        size_t idx = ((size_t)wv * 64 + lane) * 16 + j;
        WeF[idx] = h; WeF[idx + 8] = l;
    } else if (i < CHPAD * KPAD + CHPAD * 16 + 16 * CHPAD) { // final_w (16 rows)
        int j3 = i - CHPAD * KPAD - CHPAD * 16;
        int r = j3 / CHPAD, c = j3 - r * CHPAD;
        float v = (r < NRBF && c < CAT) ? fw[r * CAT + c] : 0.f;
        unsigned short h = f32_bf16_rne(v);
        unsigned short l = f32_bf16_rne(v - bf16_f32(h));
        int wv = c >> 5, kk = c & 31;
        int lane = (kk >> 3) * 16 + r, j = kk & 7;
        size_t idx = ((size_t)wv * 64 + lane) * 16 + j;
        FwF[idx] = h; FwF[idx + 8] = l;
    }
}

// ---------------------------------------------------------------------------
// angle: s_a = dot(a_sbf[a,:], colsum(W_a)), scatter-add into sum_s[kj]
// ---------------------------------------------------------------------------
__global__ __launch_bounds__(256) void angle_kernel(
    const float* __restrict__ a_sbf, const int* __restrict__ kj_idx,
    const float* __restrict__ W_a, float* __restrict__ sum_s, int A)
{
    __shared__ float wsum[ADIM];
    int tid = threadIdx.x;
    if (tid < ADIM) {
        float s = 0.f;
        #pragma unroll
        for (int b = 0; b < NBIL; ++b) s += W_a[b * ADIM + tid];
        wsum[tid] = s;
    }
    __syncthreads();

    int a = blockIdx.x * 256 + tid;
    if (a >= A) return;

    const float* row = a_sbf + (size_t)a * ADIM;
    float s = 0.f;
    #pragma unroll
    for (int d2 = 0; d2 < ADIM / 2; ++d2) {
        float2 v = *reinterpret_cast<const float2*>(row + d2 * 2);
        s += v.x * wsum[d2 * 2] + v.y * wsum[d2 * 2 + 1];
    }
    atomicAdd(&sum_s[kj_idx[a]], s);
}

// Zero-instruction opaque pin (kept from round 7 — it helped scheduling).
#define PIN_WEIGHTS()                                                          \
    asm volatile("" :                                                         \
        "+v"(wfh[0]), "+v"(wfh[1]), "+v"(wfh[2]), "+v"(wfh[3]), "+v"(wfh[4]), \
        "+v"(wfh[5]), "+v"(wfh[6]), "+v"(wfh[7]), "+v"(wfh[8]),               \
        "+v"(wfl[0]), "+v"(wfl[1]), "+v"(wfl[2]), "+v"(wfl[3]), "+v"(wfl[4]), \
        "+v"(wfl[5]), "+v"(wfl[6]), "+v"(wfl[7]), "+v"(wfl[8]),               \
        "+v"(weh), "+v"(wel), "+v"(fwh), "+v"(fwl))

// ---------------------------------------------------------------------------
// edge: 32-edge tiles, 5 waves. R7 math + double-buffered m staging:
// iteration t stages tile t+1 (from prefetched regs) into buf p^1 BEFORE
// computing tile t from buf p, so the LDS-write -> barrier -> LDS-read chain
// is one full compute-phase ahead of its consumer. e_rbf and sum_s are
// per-lane prefetched. 2 barriers/tile. projp overlaid into mae (R8).
// ---------------------------------------------------------------------------
__global__ __launch_bounds__(320, 3) void edge_kernel(
    const float* __restrict__ m_ji, const float* __restrict__ e_rbf,
    const unsigned short* __restrict__ WF, const unsigned short* __restrict__ WeF,
    const unsigned short* __restrict__ FwF,
    const float* __restrict__ sum_s, float* __restrict__ out, int E, int NT)
{
    __shared__ unsigned short mhs[2][TE][MSTR];   // 19456 B
    __shared__ unsigned short mls[2][TE][MSTR];   // 19456 B
    __shared__ unsigned short maeh[TE][TSTR];     // 10752 B (projp overlaid)
    __shared__ unsigned short mael[TE][TSTR];     // 10752 B  -> 60416 B total

    const int tid = threadIdx.x;
    const int l   = tid & 63;
    const int wv  = __builtin_amdgcn_readfirstlane(tid >> 6);
    const int l31 = l & 31;
    const int hi5 = l >> 5;
    const int GD  = gridDim.x;

    // ---- persistent weight fragments (normal loads, then opaque pin) -----
    bf16x8 wfh[9], wfl[9];
    #pragma unroll
    for (int ks = 0; ks < 9; ++ks) {
        const unsigned short* p = WF + ((size_t)(wv * 9 + ks) * 64 + l) * 16;
        wfh[ks] = *reinterpret_cast<const bf16x8*>(p);
        wfl[ks] = *reinterpret_cast<const bf16x8*>(p + 8);
    }
    const unsigned short* pe = WeF + ((size_t)wv * 64 + l) * 16;
    bf16x8 weh = *reinterpret_cast<const bf16x8*>(pe);
    bf16x8 wel = *reinterpret_cast<const bf16x8*>(pe + 8);
    const unsigned short* pf = FwF + ((size_t)wv * 64 + l) * 16;
    bf16x8 fwh = *reinterpret_cast<const bf16x8*>(pf);
    bf16x8 fwl = *reinterpret_cast<const bf16x8*>(pf + 8);
    PIN_WEIGHTS();

    // ---- one-time LDS init: bias/pad cols 134..143 for BOTH buffers ------
    if (tid < 160) {
        int r = tid / 5, j = tid - r * 5;
        #pragma unroll
        for (int b = 0; b < 2; ++b) {
            *reinterpret_cast<unsigned*>(&mhs[b][r][134 + 2 * j]) = (j == 0) ? 0x00003F80u : 0u;
            *reinterpret_cast<unsigned*>(&mls[b][r][134 + 2 * j]) = 0u;
        }
    }

    // ---- per-lane prefetch state -----------------------------------------
    float2 mpre[7];
    float2 er01, er23, er45;   // e_rbf of this lane's edge (hi5==0 lanes)
    float  ssp;                // sum_s for reduce mapping (tid<192)

#define LOADM(T)                                                              \
    do { int tt = (T);                                                        \
        const float2* mb = reinterpret_cast<const float2*>(m_ji + (size_t)tt * TE * CAT); \
        int nv2 = min(TE, E - tt * TE) * 67;                                  \
        _Pragma("unroll")                                                     \
        for (int i_ = 0; i_ < 7; ++i_) {                                      \
            int f_ = tid + i_ * 320;                                          \
            mpre[i_] = (f_ < nv2) ? mb[f_] : make_float2(0.f, 0.f);           \
        }                                                                     \
    } while (0)

#define LOADE(T)                                                              \
    do { int tt = (T);                                                        \
        er01 = make_float2(0.f, 0.f); er23 = er01; er45 = er01;               \
        int e_ = tt * TE + l31;                                               \
        if (e_ < E && hi5 == 0) {                                             \
            const float* ep_ = e_rbf + (size_t)e_ * NRBF;                     \
            er01 = *reinterpret_cast<const float2*>(ep_);                     \
            er23 = *reinterpret_cast<const float2*>(ep_ + 2);                 \
            er45 = *reinterpret_cast<const float2*>(ep_ + 4);                 \
        }                                                                     \
    } while (0)

#define LOADSS(T)                                                             \
    do { int tt = (T);                                                        \
        ssp = 0.f;                                                            \
        if (tid < 192) {                                                      \
            int eo_ = tt * TE + tid / 6;                                      \
            if (eo_ < E) ssp = sum_s[eo_];                                    \
        }                                                                     \
    } while (0)

#define STAGE(B)                                                              \
    do { int b_ = (B);                                                        \
        _Pragma("unroll")                                                     \
        for (int i_ = 0; i_ < 7; ++i_) {                                      \
            int f_ = tid + i_ * 320;                                          \
            if (f_ < M2) {                                                    \
                int r_ = f_ / 67, c_ = f_ - r_ * 67;                          \
                unsigned h_, lo_; split_pack(mpre[i_].x, mpre[i_].y, h_, lo_);\
                *reinterpret_cast<unsigned*>(&mhs[b_][r_][2 * c_]) = h_;      \
                *reinterpret_cast<unsigned*>(&mls[b_][r_][2 * c_]) = lo_;     \
            }                                                                 \
        }                                                                     \
    } while (0)

    // ---- prologue: stage t0 into buf 0, prefetch t1 ----------------------
    int p = 0;
    {
        int t0 = blockIdx.x;
        LOADM(t0); LOADE(t0); LOADSS(t0);
        STAGE(0);
        __syncthreads();
        if (t0 + GD < NT) LOADM(t0 + GD);
    }

    for (int t = blockIdx.x; t < NT; t += GD) {
        const int e0 = t * TE;
        PIN_WEIGHTS();

        // ---- 1. build eb frags + latch ss for tile t ---------------------
        bf16x8 ebh, ebl;
        {
            unsigned h0, h1, h2, q0, q1, q2;
            split_pack(er01.x, er01.y, h0, q0);
            split_pack(er23.x, er23.y, h1, q1);
            split_pack(er45.x, er45.y, h2, q2);
            ebh = upack(h0, h1, h2, 0);
            ebl = upack(q0, q1, q2, 0);
        }
        const float ss_cur = ssp;

        // ---- 2. stage tile t+1 into buf p^1 (overlaps compute of t) ------
        const bool has_next = (t + GD < NT);
        if (has_next) STAGE(p ^ 1);

        // ---- 3. issue prefetch loads for t+1 (er/ss) and t+2 (m) ---------
        if (has_next) { LOADE(t + GD); LOADSS(t + GD); }
        if (t + 2 * GD < NT) LOADM(t + 2 * GD);

        // ---- 4. MFMA1: x = Wm.m (+bias) on buf p -------------------------
        f32x16 acc  = {0,0,0,0,0,0,0,0,0,0,0,0,0,0,0,0};
        f32x16 acct = {0,0,0,0,0,0,0,0,0,0,0,0,0,0,0,0};
        #pragma unroll
        for (int ks = 0; ks < 9; ++ks) {
            bf16x8 bh = *reinterpret_cast<const bf16x8*>(&mhs[p][l31][ks * 16 + hi5 * 8]);
            bf16x8 bl = *reinterpret_cast<const bf16x8*>(&mls[p][l31][ks * 16 + hi5 * 8]);
            acc = __builtin_amdgcn_mfma_f32_32x32x16_bf16(wfh[ks], bh, acc, 0, 0, 0);
            acc = __builtin_amdgcn_mfma_f32_32x32x16_bf16(wfl[ks], bh, acc, 0, 0, 0);
            acc = __builtin_amdgcn_mfma_f32_32x32x16_bf16(wfh[ks], bl, acc, 0, 0, 0);
        }
        // ---- te = We . eb (per-lane-built B frags) -----------------------
        acct = __builtin_amdgcn_mfma_f32_32x32x16_bf16(weh, ebh, acct, 0, 0, 0);
        acct = __builtin_amdgcn_mfma_f32_32x32x16_bf16(wel, ebh, acct, 0, 0, 0);
        acct = __builtin_amdgcn_mfma_f32_32x32x16_bf16(weh, ebl, acct, 0, 0, 0);

        // ---- mae = silu(x)*te -> split -> wave-private LDS slice ---------
        #pragma unroll
        for (int q = 0; q < 4; ++q) {
            float mz[4];
            #pragma unroll
            for (int i = 0; i < 4; ++i) {
                float x  = acc[q * 4 + i];
                float sg = x / (1.f + __expf(-x));
                mz[i] = sg * acct[q * 4 + i];
            }
            unsigned h0, h1, q0, q1;
            split_pack(mz[0], mz[1], h0, q0);
            split_pack(mz[2], mz[3], h1, q1);
            const int cq = 32 * wv + 8 * q + 4 * hi5;
            *reinterpret_cast<uint2*>(&maeh[l31][cq]) = make_uint2(h0, h1);
            *reinterpret_cast<uint2*>(&mael[l31][cq]) = make_uint2(q0, q1);
        }

        // ---- MFMA3: wave reads ONLY its own mae slice; projp overlaid ----
        #pragma unroll
        for (int nt = 0; nt < 2; ++nt) {
            f32x4 a3 = {0, 0, 0, 0};
            const int mr = nt * 16 + (l & 15);
            bf16x8 bh = *reinterpret_cast<const bf16x8*>(&maeh[mr][32 * wv + (l >> 4) * 8]);
            bf16x8 bl = *reinterpret_cast<const bf16x8*>(&mael[mr][32 * wv + (l >> 4) * 8]);
            a3 = __builtin_amdgcn_mfma_f32_16x16x32_bf16(fwh, bh, a3, 0, 0, 0);
            a3 = __builtin_amdgcn_mfma_f32_16x16x32_bf16(fwl, bh, a3, 0, 0, 0);
            a3 = __builtin_amdgcn_mfma_f32_16x16x32_bf16(fwh, bl, a3, 0, 0, 0);
            const int g4 = l >> 4, es = nt * 16 + (l & 15);
            if (g4 == 0) {
                *reinterpret_cast<f32x4*>(&maeh[es][32 * wv]) = a3;          // rows 0-3
            } else if (g4 == 1) {
                *reinterpret_cast<float*>(&maeh[es][32 * wv + 8])  = a3[0];  // row 4
                *reinterpret_cast<float*>(&maeh[es][32 * wv + 10]) = a3[1];  // row 5
            }
        }
        __syncthreads();   // barrier 1: projp ready AND buf p^1 staged

        // ---- cross-wave reduce + scale + store (ss prefetched) -----------
        if (tid < 192) {
            const int es = tid / 6, r = tid - es * 6;
            const int eo = e0 + es;
            if (eo < E) {
                float vsum = 0.f;
                #pragma unroll
                for (int w2 = 0; w2 < 5; ++w2)
                    vsum += *reinterpret_cast<const float*>(&maeh[es][32 * w2 + 2 * r]);
                out[(size_t)eo * NRBF + r] = vsum * ss_cur;
            }
        }
        __syncthreads();   // barrier 2: reduce done, mae/projp free
        p ^= 1;
    }
#undef LOADM
#undef LOADE
#undef LOADSS
#undef STAGE
}

// ---------------------------------------------------------------------------
extern "C" void kernel_launch(void* const* d_in, const int* in_sizes, int n_in,
                              void* d_out, int out_size, void* d_ws, size_t ws_size,
                              hipStream_t stream)
{
    const float* m_ji    = (const float*)d_in[0];
    // d_in[1] nbr_list, d_in[2] angle_list: unused by the reference math
    const float* e_rbf   = (const float*)d_in[3];
    const float* a_sbf   = (const float*)d_in[4];
    const int*   kj_idx  = (const int*)  d_in[5];
    const float* W_m     = (const float*)d_in[6];
    const float* b_m     = (const float*)d_in[7];
    const float* W_e     = (const float*)d_in[8];
    const float* W_a     = (const float*)d_in[9];
    const float* final_w = (const float*)d_in[10];
    float* out = (float*)d_out;

    const int E  = in_sizes[0] / CAT;
    const int A  = in_sizes[5];
    const int NT = (E + TE - 1) / TE;

    // workspace layout
    char* ws = (char*)d_ws;
    float* sum_s = (float*)ws;
    size_t off = ((size_t)E * 4 + 255) & ~(size_t)255;
    unsigned short* WF  = (unsigned short*)(ws + off); off += (size_t)5 * 9 * 64 * 16 * 2;
    unsigned short* WeF = (unsigned short*)(ws + off); off += (size_t)5 * 64 * 16 * 2;
    unsigned short* FwF = (unsigned short*)(ws + off); off += (size_t)5 * 64 * 16 * 2;

    hipMemsetAsync(sum_s, 0, (size_t)E * sizeof(float), stream);

    const int prep_n = CHPAD * KPAD + CHPAD * 16 + 16 * CHPAD;
    prep_kernel<<<(prep_n + 255) / 256, 256, 0, stream>>>(
        W_m, b_m, W_e, final_w, WF, WeF, FwF);
    angle_kernel<<<(A + 255) / 256, 256, 0, stream>>>(a_sbf, kj_idx, W_a, sum_s, A);

    int grid = 512; if (grid > NT) grid = NT;
    edge_kernel<<<grid, 320, 0, stream>>>(m_ji, e_rbf, WF, WeF, FwF,
                                          sum_s, out, E, NT);
}

// Round 11
// 181.828 us; speedup vs baseline: 1.5820x; 1.2312x over previous
//
#include <hip/hip_runtime.h>
#include <math.h>

#define CAT    134
#define NRBF   6
#define ADIM   42
#define NBIL   8
#define KPAD   144      // 9 k-steps of 16 (k=134 is the bias column)
#define CHPAD  160      // 5 groups x 32 channels
#define MSTR   152      // m LDS row stride (shorts): 304 B, 16B-aligned
#define TSTR   168      // mae row stride (shorts): 336 B, 16B-aligned
#define TE     32       // edges per tile
#define M2     (TE * 67)   // float2 count of one m tile (32*134/2)

typedef __bf16 bf16x8 __attribute__((ext_vector_type(8)));
typedef float  f32x16 __attribute__((ext_vector_type(16)));
typedef float  f32x4  __attribute__((ext_vector_type(4)));

__device__ __forceinline__ unsigned short f32_bf16_rne(float x) {
    union { float f; unsigned u; } v; v.f = x;
    unsigned u = v.u;
    u += 0x7FFFu + ((u >> 16) & 1u);
    return (unsigned short)(u >> 16);
}
__device__ __forceinline__ float bf16_f32(unsigned short h) {
    union { float f; unsigned u; } v; v.u = ((unsigned)h) << 16;
    return v.f;
}
// trunc split: a = hi + lo, |err| ~ 2^-17 |a|
__device__ __forceinline__ void split_pack(float a, float b, unsigned& ph, unsigned& pl) {
    unsigned ua = __float_as_uint(a), ub = __float_as_uint(b);
    ph = (ua >> 16) | (ub & 0xffff0000u);
    float ra = a - __uint_as_float(ua & 0xffff0000u);
    float rb = b - __uint_as_float(ub & 0xffff0000u);
    pl = (__float_as_uint(ra) >> 16) | (__float_as_uint(rb) & 0xffff0000u);
}
__device__ __forceinline__ bf16x8 upack(unsigned a, unsigned b, unsigned c, unsigned d) {
    union { unsigned u[4]; bf16x8 v; } t;
    t.u[0] = a; t.u[1] = b; t.u[2] = c; t.u[3] = d;
    return t.v;
}

// ---------------------------------------------------------------------------
// prep: pack weights into FRAGMENT-MAJOR layout (5 groups incl. tail group 4)
// ---------------------------------------------------------------------------
__global__ __launch_bounds__(256) void prep_kernel(
    const float* __restrict__ Wm, const float* __restrict__ bm,
    const float* __restrict__ We, const float* __restrict__ fw,
    unsigned short* __restrict__ WF, unsigned short* __restrict__ WeF,
    unsigned short* __restrict__ FwF)
{
    int i = blockIdx.x * 256 + threadIdx.x;
    if (i < CHPAD * KPAD) {                                  // W_m (+bias col)
        int c = i / KPAD, k = i - c * KPAD;
        float v = 0.f;
        if (c < CAT) {
            if (k < CAT) v = Wm[c * CAT + k];
            else if (k == CAT) v = bm[c];
        }
        unsigned short h = f32_bf16_rne(v);
        unsigned short l = f32_bf16_rne(v - bf16_f32(h));
        int wv = c >> 5, l31 = c & 31, ks = k >> 4;
        int lane = ((k >> 3) & 1) * 32 + l31, j = k & 7;
        size_t idx = ((size_t)(wv * 9 + ks) * 64 + lane) * 16 + j;
        WF[idx] = h; WF[idx + 8] = l;
    } else if (i < CHPAD * KPAD + CHPAD * 16) {              // W_e (K -> 16)
        int j2 = i - CHPAD * KPAD; int c = j2 >> 4, r = j2 & 15;
        float v = (c < CAT && r < NRBF) ? We[c * NRBF + r] : 0.f;
        unsigned short h = f32_bf16_rne(v);
        unsigned short l = f32_bf16_rne(v - bf16_f32(h));
        int wv = c >> 5, l31 = c & 31;
        int lane = (r >> 3) * 32 + l31, j = r & 7;
        size_t idx = ((size_t)wv * 64 + lane) * 16 + j;
        WeF[idx] = h; WeF[idx + 8] = l;
    } else if (i < CHPAD * KPAD + CHPAD * 16 + 16 * CHPAD) { // final_w (16 rows)
        int j3 = i - CHPAD * KPAD - CHPAD * 16;
        int r = j3 / CHPAD, c = j3 - r * CHPAD;
        float v = (r < NRBF && c < CAT) ? fw[r * CAT + c] : 0.f;
        unsigned short h = f32_bf16_rne(v);
        unsigned short l = f32_bf16_rne(v - bf16_f32(h));
        int wv = c >> 5, kk = c & 31;
        int lane = (kk >> 3) * 16 + r, j = kk & 7;
        size_t idx = ((size_t)wv * 64 + lane) * 16 + j;
        FwF[idx] = h; FwF[idx + 8] = l;
    }
}

// ---------------------------------------------------------------------------
// angle: s_a = dot(a_sbf[a,:], colsum(W_a)), scatter-add into sum_s[kj]
// ---------------------------------------------------------------------------
__global__ __launch_bounds__(256) void angle_kernel(
    const float* __restrict__ a_sbf, const int* __restrict__ kj_idx,
    const float* __restrict__ W_a, float* __restrict__ sum_s, int A)
{
    __shared__ float wsum[ADIM];
    int tid = threadIdx.x;
    if (tid < ADIM) {
        float s = 0.f;
        #pragma unroll
        for (int b = 0; b < NBIL; ++b) s += W_a[b * ADIM + tid];
        wsum[tid] = s;
    }
    __syncthreads();

    int a = blockIdx.x * 256 + tid;
    if (a >= A) return;

    const float* row = a_sbf + (size_t)a * ADIM;
    float s = 0.f;
    #pragma unroll
    for (int d2 = 0; d2 < ADIM / 2; ++d2) {
        float2 v = *reinterpret_cast<const float2*>(row + d2 * 2);
        s += v.x * wsum[d2 * 2] + v.y * wsum[d2 * 2 + 1];
    }
    atomicAdd(&sum_s[kj_idx[a]], s);
}

// Zero-instruction opaque pin (R7-validated).
#define PIN_WEIGHTS()                                                          \
    asm volatile("" :                                                         \
        "+v"(wfh[0]), "+v"(wfh[1]), "+v"(wfh[2]), "+v"(wfh[3]), "+v"(wfh[4]), \
        "+v"(wfh[5]), "+v"(wfh[6]), "+v"(wfh[7]), "+v"(wfh[8]),               \
        "+v"(wfl[0]), "+v"(wfl[1]), "+v"(wfl[2]), "+v"(wfl[3]), "+v"(wfl[4]), \
        "+v"(wfl[5]), "+v"(wfl[6]), "+v"(wfl[7]), "+v"(wfl[8]),               \
        "+v"(weh), "+v"(wel), "+v"(fwh), "+v"(fwl))

// ---------------------------------------------------------------------------
// edge: 32-edge tiles, **4 waves (256 thr)** so TWO blocks co-reside per CU
// (2 waves/SIMD balanced). Waves 0-3 own channel groups 0-3; tail group 4
// (channels 128-133) handled by one rotating wave per tile (A-frags reloaded
// from L2, te via fp32 VALU from wave-uniform W_e scalars). R7 math, 2
// barriers/tile, prefetch under MFMA, projp overlaid into mae.
// ---------------------------------------------------------------------------
__global__ __launch_bounds__(256, 2) void edge_kernel(
    const float* __restrict__ m_ji, const float* __restrict__ e_rbf,
    const float* __restrict__ We_raw,
    const unsigned short* __restrict__ WF, const unsigned short* __restrict__ WeF,
    const unsigned short* __restrict__ FwF,
    const float* __restrict__ sum_s, float* __restrict__ out, int E, int NT)
{
    __shared__ unsigned short mhs[TE][MSTR];    //  9728 B
    __shared__ unsigned short mls[TE][MSTR];    //  9728 B
    __shared__ unsigned short maeh[TE][TSTR];   // 10752 B (proj overlaid)
    __shared__ unsigned short mael[TE][TSTR];   // 10752 B  -> 40960 B total

    const int tid = threadIdx.x;
    const int l   = tid & 63;
    const int wv  = __builtin_amdgcn_readfirstlane(tid >> 6);  // 0..3
    const int l31 = l & 31;
    const int hi5 = l >> 5;
    const int GD  = gridDim.x;

    // ---- resident weight fragments for this wave's main group ------------
    bf16x8 wfh[9], wfl[9];
    #pragma unroll
    for (int ks = 0; ks < 9; ++ks) {
        const unsigned short* p = WF + ((size_t)(wv * 9 + ks) * 64 + l) * 16;
        wfh[ks] = *reinterpret_cast<const bf16x8*>(p);
        wfl[ks] = *reinterpret_cast<const bf16x8*>(p + 8);
    }
    const unsigned short* pe = WeF + ((size_t)wv * 64 + l) * 16;
    bf16x8 weh = *reinterpret_cast<const bf16x8*>(pe);
    bf16x8 wel = *reinterpret_cast<const bf16x8*>(pe + 8);
    const unsigned short* pf = FwF + ((size_t)wv * 64 + l) * 16;
    bf16x8 fwh = *reinterpret_cast<const bf16x8*>(pf);
    bf16x8 fwl = *reinterpret_cast<const bf16x8*>(pf + 8);
    PIN_WEIGHTS();

    // ---- wave-uniform W_e scalars for tail te (rows 128..133) -> SGPRs ---
    float we4[6][6];
    #pragma unroll
    for (int r0 = 0; r0 < 6; ++r0)
        #pragma unroll
        for (int r = 0; r < 6; ++r)
            we4[r0][r] = We_raw[(size_t)(128 + r0) * NRBF + r];

    // ---- one-time LDS init: m bias/pad cols 134..143 ---------------------
    if (tid < 160) {
        int r = tid / 5, j = tid - r * 5;
        *reinterpret_cast<unsigned*>(&mhs[r][134 + 2 * j]) = (j == 0) ? 0x00003F80u : 0u;
        *reinterpret_cast<unsigned*>(&mls[r][134 + 2 * j]) = 0u;
    }

    // ---- per-lane prefetch state -----------------------------------------
    float2 mpre[9];
    float2 er01, er23, er45;   // e_rbf of edge (e0 + l31), ALL lanes
    float  ssp;

#define LOADM(T)                                                              \
    do { int tt = (T);                                                        \
        const float2* mb = reinterpret_cast<const float2*>(m_ji + (size_t)tt * TE * CAT); \
        int nv2 = min(TE, E - tt * TE) * 67;                                  \
        _Pragma("unroll")                                                     \
        for (int i_ = 0; i_ < 9; ++i_) {                                      \
            int f_ = tid + i_ * 256;                                          \
            mpre[i_] = (f_ < nv2) ? mb[f_] : make_float2(0.f, 0.f);           \
        }                                                                     \
    } while (0)

#define LOADE(T)                                                              \
    do { int tt = (T);                                                        \
        er01 = make_float2(0.f, 0.f); er23 = er01; er45 = er01;               \
        int e_ = tt * TE + l31;                                               \
        if (e_ < E) {                                                         \
            const float* ep_ = e_rbf + (size_t)e_ * NRBF;                     \
            er01 = *reinterpret_cast<const float2*>(ep_);                     \
            er23 = *reinterpret_cast<const float2*>(ep_ + 2);                 \
            er45 = *reinterpret_cast<const float2*>(ep_ + 4);                 \
        }                                                                     \
    } while (0)

#define LOADSS(T)                                                             \
    do { int tt = (T);                                                        \
        ssp = 0.f;                                                            \
        if (tid < 192) {                                                      \
            int eo_ = tt * TE + tid / 6;                                      \
            if (eo_ < E) ssp = sum_s[eo_];                                    \
        }                                                                     \
    } while (0)

    // ---- prologue: prefetch tile t0 ---------------------------------------
    {
        int t0 = blockIdx.x;
        LOADM(t0); LOADE(t0); LOADSS(t0);
    }

    int it = 0;
    for (int t = blockIdx.x; t < NT; t += GD, ++it) {
        const int e0 = t * TE;
        PIN_WEIGHTS();

        // ---- latch this tile's er (tail te) + ss; build eb frags ---------
        float er_s0 = er01.x, er_s1 = er01.y, er_s2 = er23.x,
              er_s3 = er23.y, er_s4 = er45.x, er_s5 = er45.y;
        const float ss_cur = ssp;
        bf16x8 ebh, ebl;
        {
            unsigned h0, h1, h2, q0, q1, q2;
            split_pack(er01.x, er01.y, h0, q0);
            split_pack(er23.x, er23.y, h1, q1);
            split_pack(er45.x, er45.y, h2, q2);
            if (hi5) { h0 = h1 = h2 = q0 = q1 = q2 = 0; }   // k 8..15 pad
            ebh = upack(h0, h1, h2, 0);
            ebl = upack(q0, q1, q2, 0);
        }

        // ---- stage m tile -> split-bf16 LDS (once per value) -------------
        #pragma unroll
        for (int i = 0; i < 9; ++i) {
            int f = tid + i * 256;
            if (f < M2) {
                int r = f / 67, c = f - r * 67;
                unsigned h, lo2; split_pack(mpre[i].x, mpre[i].y, h, lo2);
                *reinterpret_cast<unsigned*>(&mhs[r][2 * c]) = h;
                *reinterpret_cast<unsigned*>(&mls[r][2 * c]) = lo2;
            }
        }
        __syncthreads();   // barrier A: tile staged

        // ---- issue next tile's global loads (ride under MFMA) ------------
        if (t + GD < NT) { LOADM(t + GD); LOADE(t + GD); LOADSS(t + GD); }

        // ---- MFMA1 main: x = Wm.m (+bias) --------------------------------
        f32x16 acc  = {0,0,0,0,0,0,0,0,0,0,0,0,0,0,0,0};
        f32x16 acct = {0,0,0,0,0,0,0,0,0,0,0,0,0,0,0,0};
        #pragma unroll
        for (int ks = 0; ks < 9; ++ks) {
            bf16x8 bh = *reinterpret_cast<const bf16x8*>(&mhs[l31][ks * 16 + hi5 * 8]);
            bf16x8 bl = *reinterpret_cast<const bf16x8*>(&mls[l31][ks * 16 + hi5 * 8]);
            acc = __builtin_amdgcn_mfma_f32_32x32x16_bf16(wfh[ks], bh, acc, 0, 0, 0);
            acc = __builtin_amdgcn_mfma_f32_32x32x16_bf16(wfl[ks], bh, acc, 0, 0, 0);
            acc = __builtin_amdgcn_mfma_f32_32x32x16_bf16(wfh[ks], bl, acc, 0, 0, 0);
        }
        acct = __builtin_amdgcn_mfma_f32_32x32x16_bf16(weh, ebh, acct, 0, 0, 0);
        acct = __builtin_amdgcn_mfma_f32_32x32x16_bf16(wel, ebh, acct, 0, 0, 0);
        acct = __builtin_amdgcn_mfma_f32_32x32x16_bf16(weh, ebl, acct, 0, 0, 0);

        // ---- mae main = silu(x)*te -> wave-private LDS slice -------------
        #pragma unroll
        for (int q = 0; q < 4; ++q) {
            float mz[4];
            #pragma unroll
            for (int i = 0; i < 4; ++i) {
                float x  = acc[q * 4 + i];
                float sg = x / (1.f + __expf(-x));
                mz[i] = sg * acct[q * 4 + i];
            }
            unsigned h0, h1, q0, q1;
            split_pack(mz[0], mz[1], h0, q0);
            split_pack(mz[2], mz[3], h1, q1);
            const int cq = 32 * wv + 8 * q + 4 * hi5;
            *reinterpret_cast<uint2*>(&maeh[l31][cq]) = make_uint2(h0, h1);
            *reinterpret_cast<uint2*>(&mael[l31][cq]) = make_uint2(q0, q1);
        }

        // ---- MFMA3 main: own slice -> overlay [es][32wv..] ---------------
        #pragma unroll
        for (int nt = 0; nt < 2; ++nt) {
            f32x4 a3 = {0, 0, 0, 0};
            const int mr = nt * 16 + (l & 15);
            bf16x8 bh = *reinterpret_cast<const bf16x8*>(&maeh[mr][32 * wv + (l >> 4) * 8]);
            bf16x8 bl = *reinterpret_cast<const bf16x8*>(&mael[mr][32 * wv + (l >> 4) * 8]);
            a3 = __builtin_amdgcn_mfma_f32_16x16x32_bf16(fwh, bh, a3, 0, 0, 0);
            a3 = __builtin_amdgcn_mfma_f32_16x16x32_bf16(fwl, bh, a3, 0, 0, 0);
            a3 = __builtin_amdgcn_mfma_f32_16x16x32_bf16(fwh, bl, a3, 0, 0, 0);
            const int g4 = l >> 4, es = nt * 16 + (l & 15);
            if (g4 == 0) {
                *reinterpret_cast<f32x4*>(&maeh[es][32 * wv]) = a3;
            } else if (g4 == 1) {
                *reinterpret_cast<float*>(&maeh[es][32 * wv + 8])  = a3[0];
                *reinterpret_cast<float*>(&maeh[es][32 * wv + 10]) = a3[1];
            }
        }

        // ---- TAIL group 4 (channels 128-133), one rotating wave ----------
        if (wv == ((blockIdx.x + it) & 3)) {
            f32x16 acc4 = {0,0,0,0,0,0,0,0,0,0,0,0,0,0,0,0};
            #pragma unroll 1
            for (int ks = 0; ks < 9; ++ks) {   // rolled: A-frags from L2
                const unsigned short* p4 = WF + ((size_t)(4 * 9 + ks) * 64 + l) * 16;
                bf16x8 a4h = *reinterpret_cast<const bf16x8*>(p4);
                bf16x8 a4l = *reinterpret_cast<const bf16x8*>(p4 + 8);
                bf16x8 bh = *reinterpret_cast<const bf16x8*>(&mhs[l31][ks * 16 + hi5 * 8]);
                bf16x8 bl = *reinterpret_cast<const bf16x8*>(&mls[l31][ks * 16 + hi5 * 8]);
                acc4 = __builtin_amdgcn_mfma_f32_32x32x16_bf16(a4h, bh, acc4, 0, 0, 0);
                acc4 = __builtin_amdgcn_mfma_f32_32x32x16_bf16(a4l, bh, acc4, 0, 0, 0);
                acc4 = __builtin_amdgcn_mfma_f32_32x32x16_bf16(a4h, bl, acc4, 0, 0, 0);
            }
            // te4 in fp32 VALU: reg i covers row (i&3)+8(i>>2)+4hi5
            float te4[4];
            #pragma unroll
            for (int i = 0; i < 4; ++i) {
                float dlo = er_s0 * we4[i][0] + er_s1 * we4[i][1] + er_s2 * we4[i][2]
                          + er_s3 * we4[i][3] + er_s4 * we4[i][4] + er_s5 * we4[i][5];
                float dhi = 0.f;
                if (i < 2)
                    dhi = er_s0 * we4[4 + i][0] + er_s1 * we4[4 + i][1] + er_s2 * we4[4 + i][2]
                        + er_s3 * we4[4 + i][3] + er_s4 * we4[4 + i][4] + er_s5 * we4[4 + i][5];
                te4[i] = hi5 ? dhi : dlo;
            }
            // mae4: only q==0 regs have nonzero te (rows 0-5); rest zero
            {
                float mz[4];
                #pragma unroll
                for (int i = 0; i < 4; ++i) {
                    float x  = acc4[i];
                    float sg = x / (1.f + __expf(-x));
                    mz[i] = sg * te4[i];
                }
                unsigned h0, h1, q0, q1;
                split_pack(mz[0], mz[1], h0, q0);
                split_pack(mz[2], mz[3], h1, q1);
                const int cq = 128 + 4 * hi5;
                *reinterpret_cast<uint2*>(&maeh[l31][cq]) = make_uint2(h0, h1);
                *reinterpret_cast<uint2*>(&mael[l31][cq]) = make_uint2(q0, q1);
                #pragma unroll
                for (int q = 1; q < 4; ++q) {
                    *reinterpret_cast<uint2*>(&maeh[l31][128 + 8 * q + 4 * hi5]) = make_uint2(0, 0);
                    *reinterpret_cast<uint2*>(&mael[l31][128 + 8 * q + 4 * hi5]) = make_uint2(0, 0);
                }
            }
            // tail MFMA3 -> overlay [es][128..]
            const unsigned short* pf4 = FwF + ((size_t)4 * 64 + l) * 16;
            bf16x8 fw4h = *reinterpret_cast<const bf16x8*>(pf4);
            bf16x8 fw4l = *reinterpret_cast<const bf16x8*>(pf4 + 8);
            #pragma unroll
            for (int nt = 0; nt < 2; ++nt) {
                f32x4 a3 = {0, 0, 0, 0};
                const int mr = nt * 16 + (l & 15);
                bf16x8 bh = *reinterpret_cast<const bf16x8*>(&maeh[mr][128 + (l >> 4) * 8]);
                bf16x8 bl = *reinterpret_cast<const bf16x8*>(&mael[mr][128 + (l >> 4) * 8]);
                a3 = __builtin_amdgcn_mfma_f32_16x16x32_bf16(fw4h, bh, a3, 0, 0, 0);
                a3 = __builtin_amdgcn_mfma_f32_16x16x32_bf16(fw4l, bh, a3, 0, 0, 0);
                a3 = __builtin_amdgcn_mfma_f32_16x16x32_bf16(fw4h, bl, a3, 0, 0, 0);
                const int g4 = l >> 4, es = nt * 16 + (l & 15);
                if (g4 == 0) {
                    *reinterpret_cast<f32x4*>(&maeh[es][128]) = a3;
                } else if (g4 == 1) {
                    *reinterpret_cast<float*>(&maeh[es][128 + 8])  = a3[0];
                    *reinterpret_cast<float*>(&maeh[es][128 + 10]) = a3[1];
                }
            }
        }
        __syncthreads();   // barrier B: all overlays complete

        // ---- cross-group reduce + scale + store --------------------------
        if (tid < 192) {
            const int es = tid / 6, r = tid - es * 6;
            const int eo = e0 + es;
            if (eo < E) {
                float vsum = 0.f;
                #pragma unroll
                for (int w2 = 0; w2 < 5; ++w2)
                    vsum += *reinterpret_cast<const float*>(&maeh[es][32 * w2 + 2 * r]);
                out[(size_t)eo * NRBF + r] = vsum * ss_cur;
            }
        }
    }
#undef LOADM
#undef LOADE
#undef LOADSS
}

// ---------------------------------------------------------------------------
extern "C" void kernel_launch(void* const* d_in, const int* in_sizes, int n_in,
                              void* d_out, int out_size, void* d_ws, size_t ws_size,
                              hipStream_t stream)
{
    const float* m_ji    = (const float*)d_in[0];
    // d_in[1] nbr_list, d_in[2] angle_list: unused by the reference math
    const float* e_rbf   = (const float*)d_in[3];
    const float* a_sbf   = (const float*)d_in[4];
    const int*   kj_idx  = (const int*)  d_in[5];
    const float* W_m     = (const float*)d_in[6];
    const float* b_m     = (const float*)d_in[7];
    const float* W_e     = (const float*)d_in[8];
    const float* W_a     = (const float*)d_in[9];
    const float* final_w = (const float*)d_in[10];
    float* out = (float*)d_out;

    const int E  = in_sizes[0] / CAT;
    const int A  = in_sizes[5];
    const int NT = (E + TE - 1) / TE;

    // workspace layout
    char* ws = (char*)d_ws;
    float* sum_s = (float*)ws;
    size_t off = ((size_t)E * 4 + 255) & ~(size_t)255;
    unsigned short* WF  = (unsigned short*)(ws + off); off += (size_t)5 * 9 * 64 * 16 * 2;
    unsigned short* WeF = (unsigned short*)(ws + off); off += (size_t)5 * 64 * 16 * 2;
    unsigned short* FwF = (unsigned short*)(ws + off); off += (size_t)5 * 64 * 16 * 2;

    hipMemsetAsync(sum_s, 0, (size_t)E * sizeof(float), stream);

    const int prep_n = CHPAD * KPAD + CHPAD * 16 + 16 * CHPAD;
    prep_kernel<<<(prep_n + 255) / 256, 256, 0, stream>>>(
        W_m, b_m, W_e, final_w, WF, WeF, FwF);
    angle_kernel<<<(A + 255) / 256, 256, 0, stream>>>(a_sbf, kj_idx, W_a, sum_s, A);

    int grid = 2048; if (grid > NT) grid = NT;
    edge_kernel<<<grid, 256, 0, stream>>>(m_ji, e_rbf, W_e, WF, WeF, FwF,
                                          sum_s, out, E, NT);
}

// Round 12
// 167.350 us; speedup vs baseline: 1.7189x; 1.0865x over previous
//
#include <hip/hip_runtime.h>
#include <math.h>

#define CAT    134
#define NRBF   6
#define ADIM   42
#define NBIL   8
#define KPAD   144      // 9 k-steps of 16 (k=134 is the bias column)
#define CHPAD  160      // 5 groups x 32 channels
#define MSTR   152      // m LDS row stride (shorts): 304 B, 16B-aligned
#define TSTR   168      // mae row stride (shorts): 336 B, 16B-aligned
#define TE     32       // edges per tile
#define M2     (TE * 67)   // float2 count of one m tile (32*134/2)

typedef __bf16 bf16x8 __attribute__((ext_vector_type(8)));
typedef float  f32x16 __attribute__((ext_vector_type(16)));
typedef float  f32x4  __attribute__((ext_vector_type(4)));

__device__ __forceinline__ unsigned short f32_bf16_rne(float x) {
    union { float f; unsigned u; } v; v.f = x;
    unsigned u = v.u;
    u += 0x7FFFu + ((u >> 16) & 1u);
    return (unsigned short)(u >> 16);
}
__device__ __forceinline__ float bf16_f32(unsigned short h) {
    union { float f; unsigned u; } v; v.u = ((unsigned)h) << 16;
    return v.f;
}
// trunc split: a = hi + lo, |err| ~ 2^-17 |a|
__device__ __forceinline__ void split_pack(float a, float b, unsigned& ph, unsigned& pl) {
    unsigned ua = __float_as_uint(a), ub = __float_as_uint(b);
    ph = (ua >> 16) | (ub & 0xffff0000u);
    float ra = a - __uint_as_float(ua & 0xffff0000u);
    float rb = b - __uint_as_float(ub & 0xffff0000u);
    pl = (__float_as_uint(ra) >> 16) | (__float_as_uint(rb) & 0xffff0000u);
}
__device__ __forceinline__ bf16x8 upack(unsigned a, unsigned b, unsigned c, unsigned d) {
    union { unsigned u[4]; bf16x8 v; } t;
    t.u[0] = a; t.u[1] = b; t.u[2] = c; t.u[3] = d;
    return t.v;
}

// ---------------------------------------------------------------------------
// prep: pack weights into FRAGMENT-MAJOR layout (5 groups incl. tail group 4)
// ---------------------------------------------------------------------------
__global__ __launch_bounds__(256) void prep_kernel(
    const float* __restrict__ Wm, const float* __restrict__ bm,
    const float* __restrict__ We, const float* __restrict__ fw,
    unsigned short* __restrict__ WF, unsigned short* __restrict__ WeF,
    unsigned short* __restrict__ FwF)
{
    int i = blockIdx.x * 256 + threadIdx.x;
    if (i < CHPAD * KPAD) {                                  // W_m (+bias col)
        int c = i / KPAD, k = i - c * KPAD;
        float v = 0.f;
        if (c < CAT) {
            if (k < CAT) v = Wm[c * CAT + k];
            else if (k == CAT) v = bm[c];
        }
        unsigned short h = f32_bf16_rne(v);
        unsigned short l = f32_bf16_rne(v - bf16_f32(h));
        int wv = c >> 5, l31 = c & 31, ks = k >> 4;
        int lane = ((k >> 3) & 1) * 32 + l31, j = k & 7;
        size_t idx = ((size_t)(wv * 9 + ks) * 64 + lane) * 16 + j;
        WF[idx] = h; WF[idx + 8] = l;
    } else if (i < CHPAD * KPAD + CHPAD * 16) {              // W_e (K -> 16)
        int j2 = i - CHPAD * KPAD; int c = j2 >> 4, r = j2 & 15;
        float v = (c < CAT && r < NRBF) ? We[c * NRBF + r] : 0.f;
        unsigned short h = f32_bf16_rne(v);
        unsigned short l = f32_bf16_rne(v - bf16_f32(h));
        int wv = c >> 5, l31 = c & 31;
        int lane = (r >> 3) * 32 + l31, j = r & 7;
        size_t idx = ((size_t)wv * 64 + lane) * 16 + j;
        WeF[idx] = h; WeF[idx + 8] = l;
    } else if (i < CHPAD * KPAD + CHPAD * 16 + 16 * CHPAD) { // final_w (16 rows)
        int j3 = i - CHPAD * KPAD - CHPAD * 16;
        int r = j3 / CHPAD, c = j3 - r * CHPAD;
        float v = (r < NRBF && c < CAT) ? fw[r * CAT + c] : 0.f;
        unsigned short h = f32_bf16_rne(v);
        unsigned short l = f32_bf16_rne(v - bf16_f32(h));
        int wv = c >> 5, kk = c & 31;
        int lane = (kk >> 3) * 16 + r, j = kk & 7;
        size_t idx = ((size_t)wv * 64 + lane) * 16 + j;
        FwF[idx] = h; FwF[idx + 8] = l;
    }
}

// ---------------------------------------------------------------------------
// angle: s_a = dot(a_sbf[a,:], colsum(W_a)), scatter-add into sum_s[kj]
// ---------------------------------------------------------------------------
__global__ __launch_bounds__(256) void angle_kernel(
    const float* __restrict__ a_sbf, const int* __restrict__ kj_idx,
    const float* __restrict__ W_a, float* __restrict__ sum_s, int A)
{
    __shared__ float wsum[ADIM];
    int tid = threadIdx.x;
    if (tid < ADIM) {
        float s = 0.f;
        #pragma unroll
        for (int b = 0; b < NBIL; ++b) s += W_a[b * ADIM + tid];
        wsum[tid] = s;
    }
    __syncthreads();

    int a = blockIdx.x * 256 + tid;
    if (a >= A) return;

    const float* row = a_sbf + (size_t)a * ADIM;
    float s = 0.f;
    #pragma unroll
    for (int d2 = 0; d2 < ADIM / 2; ++d2) {
        float2 v = *reinterpret_cast<const float2*>(row + d2 * 2);
        s += v.x * wsum[d2 * 2] + v.y * wsum[d2 * 2 + 1];
    }
    atomicAdd(&sum_s[kj_idx[a]], s);
}

// Zero-instruction opaque pin (R7-validated).
#define PIN_WEIGHTS()                                                          \
    asm volatile("" :                                                         \
        "+v"(wfh[0]), "+v"(wfh[1]), "+v"(wfh[2]), "+v"(wfh[3]), "+v"(wfh[4]), \
        "+v"(wfh[5]), "+v"(wfh[6]), "+v"(wfh[7]), "+v"(wfh[8]),               \
        "+v"(wfl[0]), "+v"(wfl[1]), "+v"(wfl[2]), "+v"(wfl[3]), "+v"(wfl[4]), \
        "+v"(wfl[5]), "+v"(wfl[6]), "+v"(wfl[7]), "+v"(wfl[8]),               \
        "+v"(weh), "+v"(wel), "+v"(fwh), "+v"(fwl))

// ---------------------------------------------------------------------------
// edge: 32-edge tiles, 4 waves (2 blocks/CU). R11 structure + tail group-4
// A-fragments staged ONCE into LDS (wf4s) so the per-tile tail chain is
// ds_read-fed MFMAs instead of serialized L2 loads; fw4 loads hoisted above
// the tail MFMA1 chain. 2 barriers/tile.
// ---------------------------------------------------------------------------
__global__ __launch_bounds__(256, 2) void edge_kernel(
    const float* __restrict__ m_ji, const float* __restrict__ e_rbf,
    const float* __restrict__ We_raw,
    const unsigned short* __restrict__ WF, const unsigned short* __restrict__ WeF,
    const unsigned short* __restrict__ FwF,
    const float* __restrict__ sum_s, float* __restrict__ out, int E, int NT)
{
    __shared__ unsigned short mhs[TE][MSTR];    //  9728 B
    __shared__ unsigned short mls[TE][MSTR];    //  9728 B
    __shared__ unsigned short maeh[TE][TSTR];   // 10752 B (proj overlaid)
    __shared__ unsigned short mael[TE][TSTR];   // 10752 B
    __shared__ unsigned short wf4s[9][64][16];  // 18432 B  -> 59392 B total

    const int tid = threadIdx.x;
    const int l   = tid & 63;
    const int wv  = __builtin_amdgcn_readfirstlane(tid >> 6);  // 0..3
    const int l31 = l & 31;
    const int hi5 = l >> 5;
    const int GD  = gridDim.x;

    // ---- resident weight fragments for this wave's main group ------------
    bf16x8 wfh[9], wfl[9];
    #pragma unroll
    for (int ks = 0; ks < 9; ++ks) {
        const unsigned short* p = WF + ((size_t)(wv * 9 + ks) * 64 + l) * 16;
        wfh[ks] = *reinterpret_cast<const bf16x8*>(p);
        wfl[ks] = *reinterpret_cast<const bf16x8*>(p + 8);
    }
    const unsigned short* pe = WeF + ((size_t)wv * 64 + l) * 16;
    bf16x8 weh = *reinterpret_cast<const bf16x8*>(pe);
    bf16x8 wel = *reinterpret_cast<const bf16x8*>(pe + 8);
    const unsigned short* pf = FwF + ((size_t)wv * 64 + l) * 16;
    bf16x8 fwh = *reinterpret_cast<const bf16x8*>(pf);
    bf16x8 fwl = *reinterpret_cast<const bf16x8*>(pf + 8);
    PIN_WEIGHTS();

    // ---- stage tail group-4 A-fragments into LDS (once) ------------------
    {
        const uint4* src = reinterpret_cast<const uint4*>(WF + (size_t)(4 * 9) * 64 * 16);
        uint4* dst = reinterpret_cast<uint4*>(&wf4s[0][0][0]);
        for (int f = tid; f < 9 * 64 * 2; f += 256)   // 1152 x 16B
            dst[f] = src[f];
    }

    // ---- wave-uniform W_e scalars for tail te (rows 128..133) -> SGPRs ---
    float we4[6][6];
    #pragma unroll
    for (int r0 = 0; r0 < 6; ++r0)
        #pragma unroll
        for (int r = 0; r < 6; ++r)
            we4[r0][r] = We_raw[(size_t)(128 + r0) * NRBF + r];

    // ---- one-time LDS init: m bias/pad cols 134..143 ---------------------
    if (tid < 160) {
        int r = tid / 5, j = tid - r * 5;
        *reinterpret_cast<unsigned*>(&mhs[r][134 + 2 * j]) = (j == 0) ? 0x00003F80u : 0u;
        *reinterpret_cast<unsigned*>(&mls[r][134 + 2 * j]) = 0u;
    }

    // ---- per-lane prefetch state -----------------------------------------
    float2 mpre[9];
    float2 er01, er23, er45;
    float  ssp;

#define LOADM(T)                                                              \
    do { int tt = (T);                                                        \
        const float2* mb = reinterpret_cast<const float2*>(m_ji + (size_t)tt * TE * CAT); \
        int nv2 = min(TE, E - tt * TE) * 67;                                  \
        _Pragma("unroll")                                                     \
        for (int i_ = 0; i_ < 9; ++i_) {                                      \
            int f_ = tid + i_ * 256;                                          \
            mpre[i_] = (f_ < nv2) ? mb[f_] : make_float2(0.f, 0.f);           \
        }                                                                     \
    } while (0)

#define LOADE(T)                                                              \
    do { int tt = (T);                                                        \
        er01 = make_float2(0.f, 0.f); er23 = er01; er45 = er01;               \
        int e_ = tt * TE + l31;                                               \
        if (e_ < E) {                                                         \
            const float* ep_ = e_rbf + (size_t)e_ * NRBF;                     \
            er01 = *reinterpret_cast<const float2*>(ep_);                     \
            er23 = *reinterpret_cast<const float2*>(ep_ + 2);                 \
            er45 = *reinterpret_cast<const float2*>(ep_ + 4);                 \
        }                                                                     \
    } while (0)

#define LOADSS(T)                                                             \
    do { int tt = (T);                                                        \
        ssp = 0.f;                                                            \
        if (tid < 192) {                                                      \
            int eo_ = tt * TE + tid / 6;                                      \
            if (eo_ < E) ssp = sum_s[eo_];                                    \
        }                                                                     \
    } while (0)

    // ---- prologue: prefetch tile t0 ---------------------------------------
    {
        int t0 = blockIdx.x;
        LOADM(t0); LOADE(t0); LOADSS(t0);
    }

    int it = 0;
    for (int t = blockIdx.x; t < NT; t += GD, ++it) {
        const int e0 = t * TE;
        PIN_WEIGHTS();

        // ---- latch this tile's er (tail te) + ss; build eb frags ---------
        float er_s0 = er01.x, er_s1 = er01.y, er_s2 = er23.x,
              er_s3 = er23.y, er_s4 = er45.x, er_s5 = er45.y;
        const float ss_cur = ssp;
        bf16x8 ebh, ebl;
        {
            unsigned h0, h1, h2, q0, q1, q2;
            split_pack(er01.x, er01.y, h0, q0);
            split_pack(er23.x, er23.y, h1, q1);
            split_pack(er45.x, er45.y, h2, q2);
            if (hi5) { h0 = h1 = h2 = q0 = q1 = q2 = 0; }   // k 8..15 pad
            ebh = upack(h0, h1, h2, 0);
            ebl = upack(q0, q1, q2, 0);
        }

        // ---- stage m tile -> split-bf16 LDS (once per value) -------------
        #pragma unroll
        for (int i = 0; i < 9; ++i) {
            int f = tid + i * 256;
            if (f < M2) {
                int r = f / 67, c = f - r * 67;
                unsigned h, lo2; split_pack(mpre[i].x, mpre[i].y, h, lo2);
                *reinterpret_cast<unsigned*>(&mhs[r][2 * c]) = h;
                *reinterpret_cast<unsigned*>(&mls[r][2 * c]) = lo2;
            }
        }
        __syncthreads();   // barrier A: tile staged

        // ---- issue next tile's global loads (ride under MFMA) ------------
        if (t + GD < NT) { LOADM(t + GD); LOADE(t + GD); LOADSS(t + GD); }

        // ---- MFMA1 main: x = Wm.m (+bias) --------------------------------
        f32x16 acc  = {0,0,0,0,0,0,0,0,0,0,0,0,0,0,0,0};
        f32x16 acct = {0,0,0,0,0,0,0,0,0,0,0,0,0,0,0,0};
        #pragma unroll
        for (int ks = 0; ks < 9; ++ks) {
            bf16x8 bh = *reinterpret_cast<const bf16x8*>(&mhs[l31][ks * 16 + hi5 * 8]);
            bf16x8 bl = *reinterpret_cast<const bf16x8*>(&mls[l31][ks * 16 + hi5 * 8]);
            acc = __builtin_amdgcn_mfma_f32_32x32x16_bf16(wfh[ks], bh, acc, 0, 0, 0);
            acc = __builtin_amdgcn_mfma_f32_32x32x16_bf16(wfl[ks], bh, acc, 0, 0, 0);
            acc = __builtin_amdgcn_mfma_f32_32x32x16_bf16(wfh[ks], bl, acc, 0, 0, 0);
        }
        acct = __builtin_amdgcn_mfma_f32_32x32x16_bf16(weh, ebh, acct, 0, 0, 0);
        acct = __builtin_amdgcn_mfma_f32_32x32x16_bf16(wel, ebh, acct, 0, 0, 0);
        acct = __builtin_amdgcn_mfma_f32_32x32x16_bf16(weh, ebl, acct, 0, 0, 0);

        // ---- mae main = silu(x)*te -> wave-private LDS slice -------------
        #pragma unroll
        for (int q = 0; q < 4; ++q) {
            float mz[4];
            #pragma unroll
            for (int i = 0; i < 4; ++i) {
                float x  = acc[q * 4 + i];
                float sg = x / (1.f + __expf(-x));
                mz[i] = sg * acct[q * 4 + i];
            }
            unsigned h0, h1, q0, q1;
            split_pack(mz[0], mz[1], h0, q0);
            split_pack(mz[2], mz[3], h1, q1);
            const int cq = 32 * wv + 8 * q + 4 * hi5;
            *reinterpret_cast<uint2*>(&maeh[l31][cq]) = make_uint2(h0, h1);
            *reinterpret_cast<uint2*>(&mael[l31][cq]) = make_uint2(q0, q1);
        }

        // ---- MFMA3 main: own slice -> overlay [es][32wv..] ---------------
        #pragma unroll
        for (int nt = 0; nt < 2; ++nt) {
            f32x4 a3 = {0, 0, 0, 0};
            const int mr = nt * 16 + (l & 15);
            bf16x8 bh = *reinterpret_cast<const bf16x8*>(&maeh[mr][32 * wv + (l >> 4) * 8]);
            bf16x8 bl = *reinterpret_cast<const bf16x8*>(&mael[mr][32 * wv + (l >> 4) * 8]);
            a3 = __builtin_amdgcn_mfma_f32_16x16x32_bf16(fwh, bh, a3, 0, 0, 0);
            a3 = __builtin_amdgcn_mfma_f32_16x16x32_bf16(fwl, bh, a3, 0, 0, 0);
            a3 = __builtin_amdgcn_mfma_f32_16x16x32_bf16(fwh, bl, a3, 0, 0, 0);
            const int g4 = l >> 4, es = nt * 16 + (l & 15);
            if (g4 == 0) {
                *reinterpret_cast<f32x4*>(&maeh[es][32 * wv]) = a3;
            } else if (g4 == 1) {
                *reinterpret_cast<float*>(&maeh[es][32 * wv + 8])  = a3[0];
                *reinterpret_cast<float*>(&maeh[es][32 * wv + 10]) = a3[1];
            }
        }

        // ---- TAIL group 4 (channels 128-133), one rotating wave ----------
        if (wv == ((blockIdx.x + it) & 3)) {
            // fw4 loads issued FIRST: latency hides under the MFMA1 chain
            const unsigned short* pf4 = FwF + ((size_t)4 * 64 + l) * 16;
            bf16x8 fw4h = *reinterpret_cast<const bf16x8*>(pf4);
            bf16x8 fw4l = *reinterpret_cast<const bf16x8*>(pf4 + 8);

            f32x16 acc4 = {0,0,0,0,0,0,0,0,0,0,0,0,0,0,0,0};
            #pragma unroll
            for (int ks = 0; ks < 9; ++ks) {   // A-frags from LDS (pipelined)
                bf16x8 a4h = *reinterpret_cast<const bf16x8*>(&wf4s[ks][l][0]);
                bf16x8 a4l = *reinterpret_cast<const bf16x8*>(&wf4s[ks][l][8]);
                bf16x8 bh = *reinterpret_cast<const bf16x8*>(&mhs[l31][ks * 16 + hi5 * 8]);
                bf16x8 bl = *reinterpret_cast<const bf16x8*>(&mls[l31][ks * 16 + hi5 * 8]);
                acc4 = __builtin_amdgcn_mfma_f32_32x32x16_bf16(a4h, bh, acc4, 0, 0, 0);
                acc4 = __builtin_amdgcn_mfma_f32_32x32x16_bf16(a4l, bh, acc4, 0, 0, 0);
                acc4 = __builtin_amdgcn_mfma_f32_32x32x16_bf16(a4h, bl, acc4, 0, 0, 0);
            }
            // te4 in fp32 VALU: reg i covers row (i&3)+8(i>>2)+4hi5
            float te4[4];
            #pragma unroll
            for (int i = 0; i < 4; ++i) {
                float dlo = er_s0 * we4[i][0] + er_s1 * we4[i][1] + er_s2 * we4[i][2]
                          + er_s3 * we4[i][3] + er_s4 * we4[i][4] + er_s5 * we4[i][5];
                float dhi = 0.f;
                if (i < 2)
                    dhi = er_s0 * we4[4 + i][0] + er_s1 * we4[4 + i][1] + er_s2 * we4[4 + i][2]
                        + er_s3 * we4[4 + i][3] + er_s4 * we4[4 + i][4] + er_s5 * we4[4 + i][5];
                te4[i] = hi5 ? dhi : dlo;
            }
            // mae4: only q==0 regs have nonzero te (rows 0-5); rest zero
            {
                float mz[4];
                #pragma unroll
                for (int i = 0; i < 4; ++i) {
                    float x  = acc4[i];
                    float sg = x / (1.f + __expf(-x));
                    mz[i] = sg * te4[i];
                }
                unsigned h0, h1, q0, q1;
                split_pack(mz[0], mz[1], h0, q0);
                split_pack(mz[2], mz[3], h1, q1);
                const int cq = 128 + 4 * hi5;
                *reinterpret_cast<uint2*>(&maeh[l31][cq]) = make_uint2(h0, h1);
                *reinterpret_cast<uint2*>(&mael[l31][cq]) = make_uint2(q0, q1);
                #pragma unroll
                for (int q = 1; q < 4; ++q) {
                    *reinterpret_cast<uint2*>(&maeh[l31][128 + 8 * q + 4 * hi5]) = make_uint2(0, 0);
                    *reinterpret_cast<uint2*>(&mael[l31][128 + 8 * q + 4 * hi5]) = make_uint2(0, 0);
                }
            }
            // tail MFMA3 -> overlay [es][128..]
            #pragma unroll
            for (int nt = 0; nt < 2; ++nt) {
                f32x4 a3 = {0, 0, 0, 0};
                const int mr = nt * 16 + (l & 15);
                bf16x8 bh = *reinterpret_cast<const bf16x8*>(&maeh[mr][128 + (l >> 4) * 8]);
                bf16x8 bl = *reinterpret_cast<const bf16x8*>(&mael[mr][128 + (l >> 4) * 8]);
                a3 = __builtin_amdgcn_mfma_f32_16x16x32_bf16(fw4h, bh, a3, 0, 0, 0);
                a3 = __builtin_amdgcn_mfma_f32_16x16x32_bf16(fw4l, bh, a3, 0, 0, 0);
                a3 = __builtin_amdgcn_mfma_f32_16x16x32_bf16(fw4h, bl, a3, 0, 0, 0);
                const int g4 = l >> 4, es = nt * 16 + (l & 15);
                if (g4 == 0) {
                    *reinterpret_cast<f32x4*>(&maeh[es][128]) = a3;
                } else if (g4 == 1) {
                    *reinterpret_cast<float*>(&maeh[es][128 + 8])  = a3[0];
                    *reinterpret_cast<float*>(&maeh[es][128 + 10]) = a3[1];
                }
            }
        }
        __syncthreads();   // barrier B: all overlays complete

        // ---- cross-group reduce + scale + store --------------------------
        if (tid < 192) {
            const int es = tid / 6, r = tid - es * 6;
            const int eo = e0 + es;
            if (eo < E) {
                float vsum = 0.f;
                #pragma unroll
                for (int w2 = 0; w2 < 5; ++w2)
                    vsum += *reinterpret_cast<const float*>(&maeh[es][32 * w2 + 2 * r]);
                out[(size_t)eo * NRBF + r] = vsum * ss_cur;
            }
        }
    }
#undef LOADM
#undef LOADE
#undef LOADSS
}

// ---------------------------------------------------------------------------
extern "C" void kernel_launch(void* const* d_in, const int* in_sizes, int n_in,
                              void* d_out, int out_size, void* d_ws, size_t ws_size,
                              hipStream_t stream)
{
    const float* m_ji    = (const float*)d_in[0];
    // d_in[1] nbr_list, d_in[2] angle_list: unused by the reference math
    const float* e_rbf   = (const float*)d_in[3];
    const float* a_sbf   = (const float*)d_in[4];
    const int*   kj_idx  = (const int*)  d_in[5];
    const float* W_m     = (const float*)d_in[6];
    const float* b_m     = (const float*)d_in[7];
    const float* W_e     = (const float*)d_in[8];
    const float* W_a     = (const float*)d_in[9];
    const float* final_w = (const float*)d_in[10];
    float* out = (float*)d_out;

    const int E  = in_sizes[0] / CAT;
    const int A  = in_sizes[5];
    const int NT = (E + TE - 1) / TE;

    // workspace layout
    char* ws = (char*)d_ws;
    float* sum_s = (float*)ws;
    size_t off = ((size_t)E * 4 + 255) & ~(size_t)255;
    unsigned short* WF  = (unsigned short*)(ws + off); off += (size_t)5 * 9 * 64 * 16 * 2;
    unsigned short* WeF = (unsigned short*)(ws + off); off += (size_t)5 * 64 * 16 * 2;
    unsigned short* FwF = (unsigned short*)(ws + off); off += (size_t)5 * 64 * 16 * 2;

    hipMemsetAsync(sum_s, 0, (size_t)E * sizeof(float), stream);

    const int prep_n = CHPAD * KPAD + CHPAD * 16 + 16 * CHPAD;
    prep_kernel<<<(prep_n + 255) / 256, 256, 0, stream>>>(
        W_m, b_m, W_e, final_w, WF, WeF, FwF);
    angle_kernel<<<(A + 255) / 256, 256, 0, stream>>>(a_sbf, kj_idx, W_a, sum_s, A);

    int grid = 2048; if (grid > NT) grid = NT;
    edge_kernel<<<grid, 256, 0, stream>>>(m_ji, e_rbf, W_e, WF, WeF, FwF,
                                          sum_s, out, E, NT);
}